// Round 7
// baseline (797.523 us; speedup 1.0000x reference)
//
#include <hip/hip_runtime.h>
#include <hip/hip_cooperative_groups.h>

namespace cg = cooperative_groups;

typedef unsigned short u16;
typedef __attribute__((ext_vector_type(8))) short short8;
typedef __attribute__((ext_vector_type(4))) float f32x4;
typedef __attribute__((ext_vector_type(4))) unsigned short u16x4;
typedef __attribute__((ext_vector_type(2))) unsigned u32x2;

#define NN 262144
#define CC 256
#define RR 64
#define GG 1024
#define NTILES 8192           // 32-node tiles
#define NB 1280               // cooperative grid: 5 blocks/CU x 256 CU

// LDS byte-offset swizzle for row-major [node][feat] bf16 tiles.
#define SWZ(b, n) ((b) ^ (((n) & 7) << 4))
// slab row-swizzle ([16][64] f32, 256 B rows).
#define SSWZ(b, r) ((b) ^ (((r) & 7) << 4))

// ws layout (bytes):
//   0        : 6 bf16 weight matrices (w1g,w2g,w1l,w2l,w1a,w2a), 16384 elems each
//   196608   : seg float [1024][256] (raw sums; P2 scales by 1/cnt)
//   1245184  : cnt int [1024]
//   1249280  : xbf — per-tile PRE-SWIZZLED bf16 x tiles, 16384 B each
#define XBFOFF 1249280
#define XBFSZ  ((size_t)NN * CC * 2)
#define ZBOFF 16384

static __device__ __forceinline__ u16 f2bf(float f) {
  unsigned u = __builtin_bit_cast(unsigned, f);
  u += 0x7fffu + ((u >> 16) & 1u);   // RNE
  return (u16)(u >> 16);
}

static __device__ __forceinline__ unsigned cvt_pk_bf16(float lo, float hi) {
  unsigned r;
  asm("v_cvt_pk_bf16_f32 %0, %1, %2" : "=v"(r) : "v"(lo), "v"(hi));
  return r;
}

static __device__ __forceinline__ void lgkm0() {
  __asm__ volatile("s_waitcnt lgkmcnt(0)" ::: "memory");
}

#define MFMA16(a, b, c) __builtin_amdgcn_mfma_f32_16x16x32_bf16((a), (b), (c), 0, 0, 0)

// ============================================================================
// Single kernel, 3 phases. phase==3: cooperative (grid.sync between phases);
// phase 0/1/2: same bodies as separate launches (fallback).
// Block = 32-node tile, 4 waves, feature-split; grid-stride over tiles with
// T14 pipelining: tile t+NB's inputs are loaded to REGISTERS right after
// tile t's first barrier -> every barrier's implicit vmcnt(0) drain finds
// them complete. waves_per_eu(5,5): VGPR budget 102 vs ~80 used (no spill;
// R3/R5 lesson). LDS 20480: XB 0..16384, ZB 16384..20480; P1 slabs overlay XB.
// ============================================================================
__global__ __launch_bounds__(256)
__attribute__((amdgpu_waves_per_eu(5, 5))) void k_main(
    int phase,
    const float* __restrict__ x, u16* __restrict__ wbf,
    const float* __restrict__ ws0, const float* __restrict__ ws1,
    const float* __restrict__ ws2, const float* __restrict__ ws3,
    const float* __restrict__ ws4, const float* __restrict__ ws5,
    const int* __restrict__ bidx,
    const float* __restrict__ pag, const float* __restrict__ pal,
    const float* __restrict__ paa,
    float* __restrict__ seg, int* __restrict__ cnt,
    char* __restrict__ xbf, float* __restrict__ out) {
  __shared__ __align__(16) char smem[20480];
  const int tid = threadIdx.x;
  const int wave = tid >> 6, lane = tid & 63;
  const int low = lane & 15, quad = lane >> 4;

  // ---------------- P0: weight cvt + seg/cnt zero ----------------
  if (phase == 0 || phase == 3) {
    int idx = blockIdx.x * 256 + tid;
    if (idx < 24576) {                       // 6 x 4096 f32x4 weight chunks
      int m = idx >> 12, o4 = (idx & 4095) << 2;
      const float* s = (m == 0) ? ws0 : (m == 1) ? ws1 : (m == 2) ? ws2
                     : (m == 3) ? ws3 : (m == 4) ? ws4 : ws5;
      f32x4 v = *(const f32x4*)(s + o4);
      u16x4 p;
      p[0] = f2bf(v[0]); p[1] = f2bf(v[1]); p[2] = f2bf(v[2]); p[3] = f2bf(v[3]);
      *(u16x4*)(wbf + m * 16384 + o4) = p;
    } else if (idx < 24576 + 65792) {        // zero seg (1 MB) + cnt (4 KB)
      ((f32x4*)seg)[idx - 24576] = (f32x4){0.f, 0.f, 0.f, 0.f};
    }
  }
  if (phase == 3) cg::this_grid().sync();

  // ---------------- P1: glb MLP + segment sums/counts + xbf export ----------
  if (phase == 1 || phase == 3) {
    const u16* w1 = wbf;
    const u16* w2 = wbf + 16384;
    const float alpha = pag[0];
    f32x4 xn[8];
    int lbvn = 0;
    int t0 = blockIdx.x;
    if (t0 < NTILES) {
      const float* xs = x + ((size_t)t0 << 5) * CC;
#pragma unroll
      for (int k = 0; k < 8; k++) xn[k] = *(const f32x4*)(xs + k * 1024 + tid * 4);
      lbvn = bidx[(t0 << 5) + (lane & 31)];
    }
    for (int t = t0; t < NTILES; t += gridDim.x) {
      const int lbv = lbvn;
      // stage from prefetched regs -> swizzled LDS (+ xbf export)
      char* xtile = xbf ? (xbf + ((size_t)t << 14)) : nullptr;
#pragma unroll
      for (int k = 0; k < 8; k++) {
        int f = k * 1024 + tid * 4;
        int node = f >> 8;
        u32x2 p;
        p[0] = cvt_pk_bf16(xn[k][0], xn[k][1]);
        p[1] = cvt_pk_bf16(xn[k][2], xn[k][3]);
        int off = SWZ(node * 512 + (f & 255) * 2, node);
        *(u32x2*)(smem + off) = p;
        if (xtile) *(u32x2*)(xtile + off) = p;
      }
      __syncthreads();   // B1: x visible
      // issue NEXT tile's loads (land ~3 phases before use)
      if (t + (int)gridDim.x < NTILES) {
        const float* xs = x + ((size_t)(t + gridDim.x) << 5) * CC;
#pragma unroll
        for (int k = 0; k < 8; k++) xn[k] = *(const f32x4*)(xs + k * 1024 + tid * 4);
        lbvn = bidx[((t + gridDim.x) << 5) + (lane & 31)];
      }
      // node counts (wave 0, run-length on sorted bidx)
      if (wave == 0) {
        int cur = __shfl(lbv, 0), rl = 0;
#pragma unroll
        for (int n = 0; n < 32; n++) {
          int b = __shfl(lbv, n);
          if (b != cur) { if (lane == 0) atomicAdd(cnt + cur, rl); rl = 0; cur = b; }
          rl++;
        }
        if (lane == 0) atomicAdd(cnt + cur, rl);
      }
      // layer1: wave's 16 feats x 32 nodes
      f32x4 z[2] = {};
      const u16* w1p = w1 + (wave * 16 + low) * CC;
#pragma unroll
      for (int ks = 0; ks < 8; ks++) {
        short8 wa = *(const short8*)(w1p + ks * 32 + quad * 8);
#pragma unroll
        for (int nt = 0; nt < 2; nt++) {
          int node = nt * 16 + low;
          short8 xf = *(const short8*)(smem + SWZ(node * 512 + ks * 64 + quad * 16, node));
          z[nt] = MFMA16(wa, xf, z[nt]);
        }
      }
#pragma unroll
      for (int nt = 0; nt < 2; nt++) {
        float v0 = z[nt][0], v1 = z[nt][1], v2 = z[nt][2], v3 = z[nt][3];
        v0 = v0 >= 0.f ? v0 : alpha * v0;
        v1 = v1 >= 0.f ? v1 : alpha * v1;
        v2 = v2 >= 0.f ? v2 : alpha * v2;
        v3 = v3 >= 0.f ? v3 : alpha * v3;
        int node = nt * 16 + low;
        u32x2 p;
        p[0] = cvt_pk_bf16(v0, v1);
        p[1] = cvt_pk_bf16(v2, v3);
        *(u32x2*)(smem + ZBOFF + SWZ(node * 128 + wave * 32 + quad * 8, node)) = p;
      }
      __syncthreads();   // B2: z visible; x reads drained (slab overlays XB)
      // layer2 + segment reduce, per nt
      char* slab = smem + wave * 4096;
#pragma unroll
      for (int nt = 0; nt < 2; nt++) {
        int node = nt * 16 + low;
        f32x4 g[4] = {};
#pragma unroll
        for (int ks2 = 0; ks2 < 2; ks2++) {
          short8 zf = *(const short8*)(smem + ZBOFF + SWZ(node * 128 + ks2 * 64 + quad * 16, node));
#pragma unroll
          for (int mt = 0; mt < 4; mt++) {
            short8 wa = *(const short8*)(w2 + (wave * 64 + mt * 16 + low) * RR + ks2 * 32 + quad * 8);
            g[mt] = MFMA16(wa, zf, g[mt]);
          }
        }
#pragma unroll
        for (int mt = 0; mt < 4; mt++)
          *(f32x4*)(slab + SSWZ(low * 256 + mt * 64 + quad * 16, low)) = g[mt];
        lgkm0();
        float acc = 0.f;
        int cur = __shfl(lbv, nt * 16);
#pragma unroll
        for (int n = 0; n < 16; n++) {
          int b = __shfl(lbv, nt * 16 + n);
          if (b != cur) {
            atomicAdd(seg + (size_t)cur * CC + wave * 64 + lane, acc);
            acc = 0.f; cur = b;
          }
          acc += *(const float*)(slab + SSWZ(n * 256 + lane * 4, n));
        }
        atomicAdd(seg + (size_t)cur * CC + wave * 64 + lane, acc);
        lgkm0();
      }
      __syncthreads();   // B3: slab reads drained before next tile's stage
    }
  }
  if (phase == 3) cg::this_grid().sync();

  // ---------------- P2: local MLP + gather + attn MLP + sigmoid -------------
  if (phase == 2 || phase == 3) {
    const u16* w1l = wbf + 2 * 16384;
    const u16* w2l = wbf + 3 * 16384;
    const u16* w1a = wbf + 4 * 16384;
    const u16* w2a = wbf + 5 * 16384;
    const float al = pal[0], aa = paa[0];
    f32x4 xn2[4];
    int bbn[2] = {0, 0}, ccn[2] = {0, 0};
    int t0 = blockIdx.x;
    if (t0 < NTILES) {
      if (xbf) {
        const char* gs = xbf + ((size_t)t0 << 14);
#pragma unroll
        for (int j = 0; j < 4; j++) xn2[j] = *(const f32x4*)(gs + tid * 16 + j * 4096);
      }
#pragma unroll
      for (int nt = 0; nt < 2; nt++) bbn[nt] = bidx[(t0 << 5) + nt * 16 + low];
#pragma unroll
      for (int nt = 0; nt < 2; nt++) ccn[nt] = cnt[bbn[nt]];
    }
    for (int t = t0; t < NTILES; t += gridDim.x) {
      const int node0 = t << 5;
      int bb[2] = {bbn[0], bbn[1]};
      int cc2[2] = {ccn[0], ccn[1]};
      // stage x tile
      if (xbf) {
#pragma unroll
        for (int j = 0; j < 4; j++)
          *(f32x4*)(smem + tid * 16 + j * 4096) = xn2[j];   // linear image copy
      } else {
        const float* xs = x + (size_t)node0 * CC;
#pragma unroll
        for (int k = 0; k < 8; k++) {
          int f = k * 1024 + tid * 4;
          f32x4 v = *(const f32x4*)(xs + f);
          int node = f >> 8;
          u32x2 p;
          p[0] = cvt_pk_bf16(v[0], v[1]);
          p[1] = cvt_pk_bf16(v[2], v[3]);
          *(u32x2*)(smem + SWZ(node * 512 + (f & 255) * 2, node)) = p;
        }
      }
      __syncthreads();   // B1: x visible
      // issue NEXT tile's loads
      if (t + (int)gridDim.x < NTILES) {
        int tn = t + gridDim.x;
        if (xbf) {
          const char* gs = xbf + ((size_t)tn << 14);
#pragma unroll
          for (int j = 0; j < 4; j++) xn2[j] = *(const f32x4*)(gs + tid * 16 + j * 4096);
        }
#pragma unroll
        for (int nt = 0; nt < 2; nt++) bbn[nt] = bidx[(tn << 5) + nt * 16 + low];
#pragma unroll
        for (int nt = 0; nt < 2; nt++) ccn[nt] = cnt[bbn[nt]];
      }
      // local layer1
      f32x4 z[2] = {};
      const u16* w1p = w1l + (wave * 16 + low) * CC;
#pragma unroll
      for (int ks = 0; ks < 8; ks++) {
        short8 wa = *(const short8*)(w1p + ks * 32 + quad * 8);
#pragma unroll
        for (int nt = 0; nt < 2; nt++) {
          int node = nt * 16 + low;
          short8 xf = *(const short8*)(smem + SWZ(node * 512 + ks * 64 + quad * 16, node));
          z[nt] = MFMA16(wa, xf, z[nt]);
        }
      }
#pragma unroll
      for (int nt = 0; nt < 2; nt++) {
        float v0 = z[nt][0], v1 = z[nt][1], v2 = z[nt][2], v3 = z[nt][3];
        v0 = v0 >= 0.f ? v0 : al * v0;
        v1 = v1 >= 0.f ? v1 : al * v1;
        v2 = v2 >= 0.f ? v2 : al * v2;
        v3 = v3 >= 0.f ? v3 : al * v3;
        int node = nt * 16 + low;
        u32x2 p;
        p[0] = cvt_pk_bf16(v0, v1);
        p[1] = cvt_pk_bf16(v2, v3);
        *(u32x2*)(smem + ZBOFF + SWZ(node * 128 + wave * 32 + quad * 8, node)) = p;
      }
      __syncthreads();   // B2: z visible; x reads drained (h overwrites XB)
      // local layer2 + gather + h-stage, per nt
#pragma unroll
      for (int nt = 0; nt < 2; nt++) {
        int node = nt * 16 + low;
        f32x4 loc[4] = {};
#pragma unroll
        for (int ks2 = 0; ks2 < 2; ks2++) {
          short8 zf = *(const short8*)(smem + ZBOFF + SWZ(node * 128 + ks2 * 64 + quad * 16, node));
#pragma unroll
          for (int mt = 0; mt < 4; mt++) {
            short8 wa = *(const short8*)(w2l + (wave * 64 + mt * 16 + low) * RR + ks2 * 32 + quad * 8);
            loc[mt] = MFMA16(wa, zf, loc[mt]);
          }
        }
        const float* srow = seg + (size_t)bb[nt] * CC + wave * 64;
        float inv = (cc2[nt] > 0) ? __builtin_amdgcn_rcpf((float)cc2[nt]) : 0.0f;
#pragma unroll
        for (int mt = 0; mt < 4; mt++) {
          f32x4 sv = *(const f32x4*)(srow + mt * 16 + quad * 4);
          u32x2 p;
          p[0] = cvt_pk_bf16(fmaf(sv[0], inv, loc[mt][0]),
                             fmaf(sv[1], inv, loc[mt][1]));
          p[1] = cvt_pk_bf16(fmaf(sv[2], inv, loc[mt][2]),
                             fmaf(sv[3], inv, loc[mt][3]));
          *(u32x2*)(smem + SWZ(node * 512 + wave * 128 + mt * 32 + quad * 8, node)) = p;
        }
      }
      __syncthreads();   // B3: h visible + z reads drained
      // attn layer1
      f32x4 z2[2] = {};
      const u16* w1pa = w1a + (wave * 16 + low) * CC;
#pragma unroll
      for (int ks = 0; ks < 8; ks++) {
        short8 wa = *(const short8*)(w1pa + ks * 32 + quad * 8);
#pragma unroll
        for (int nt = 0; nt < 2; nt++) {
          int node = nt * 16 + low;
          short8 hf = *(const short8*)(smem + SWZ(node * 512 + ks * 64 + quad * 16, node));
          z2[nt] = MFMA16(wa, hf, z2[nt]);
        }
      }
#pragma unroll
      for (int nt = 0; nt < 2; nt++) {
        float v0 = z2[nt][0], v1 = z2[nt][1], v2 = z2[nt][2], v3 = z2[nt][3];
        v0 = v0 >= 0.f ? v0 : aa * v0;
        v1 = v1 >= 0.f ? v1 : aa * v1;
        v2 = v2 >= 0.f ? v2 : aa * v2;
        v3 = v3 >= 0.f ? v3 : aa * v3;
        int node = nt * 16 + low;
        u32x2 p;
        p[0] = cvt_pk_bf16(v0, v1);
        p[1] = cvt_pk_bf16(v2, v3);
        *(u32x2*)(smem + ZBOFF + SWZ(node * 128 + wave * 32 + quad * 8, node)) = p;
      }
      __syncthreads();   // B4: z2 visible + h reads drained (next stage may write XB)
      // attn layer2 + sigmoid + direct store
#pragma unroll
      for (int nt = 0; nt < 2; nt++) {
        int node = nt * 16 + low;
        f32x4 o[4] = {};
#pragma unroll
        for (int ks2 = 0; ks2 < 2; ks2++) {
          short8 zf = *(const short8*)(smem + ZBOFF + SWZ(node * 128 + ks2 * 64 + quad * 16, node));
#pragma unroll
          for (int mt = 0; mt < 4; mt++) {
            short8 wa = *(const short8*)(w2a + (wave * 64 + mt * 16 + low) * RR + ks2 * 32 + quad * 8);
            o[mt] = MFMA16(wa, zf, o[mt]);
          }
        }
        float* orow = out + (size_t)(node0 + node) * CC + wave * 64;
#pragma unroll
        for (int mt = 0; mt < 4; mt++) {
#pragma unroll
          for (int i = 0; i < 4; i++)
            o[mt][i] = __builtin_amdgcn_rcpf(1.0f + __expf(-o[mt][i]));
          *(f32x4*)(orow + mt * 16 + quad * 4) = o[mt];
        }
      }
    }
  }
}

extern "C" void kernel_launch(void* const* d_in, const int* in_sizes, int n_in,
                              void* d_out, int out_size, void* d_ws, size_t ws_size,
                              hipStream_t stream) {
  (void)in_sizes; (void)n_in; (void)out_size;
  const float* x   = (const float*)d_in[0];
  const float* w1g = (const float*)d_in[1];
  const float* ag  = (const float*)d_in[2];
  const float* w2g = (const float*)d_in[3];
  const float* w1l = (const float*)d_in[4];
  const float* al  = (const float*)d_in[5];
  const float* w2l = (const float*)d_in[6];
  const float* w1a = (const float*)d_in[7];
  const float* aa  = (const float*)d_in[8];
  const float* w2a = (const float*)d_in[9];
  const int* bidx  = (const int*)d_in[10];
  float* out = (float*)d_out;

  u16* wbf   = (u16*)d_ws;
  float* seg = (float*)((char*)d_ws + 196608);
  int* cnt   = (int*)((char*)d_ws + 196608 + 1048576);
  char* xbf  = (ws_size >= (size_t)XBFOFF + XBFSZ) ? ((char*)d_ws + XBFOFF) : nullptr;

  static int coop = -1;
  if (coop < 0) {
    int mb = 0;
    hipError_t e = hipOccupancyMaxActiveBlocksPerMultiprocessor(&mb, k_main, 256, 0);
    coop = (e == hipSuccess && mb >= 5) ? 1 : 0;
  }

  int ph = 3;
  void* args[] = {&ph, &x, &wbf, &w1g, &w2g, &w1l, &w2l, &w1a, &w2a,
                  &bidx, &ag, &al, &aa, &seg, &cnt, &xbf, &out};
  if (coop) {
    hipError_t e = hipLaunchCooperativeKernel((const void*)k_main, dim3(NB),
                                              dim3(256), args, 0, stream);
    if (e == hipSuccess) return;
    coop = 0;   // capture-unsupported or occupancy refusal -> fallback
  }
  k_main<<<NB, 256, 0, stream>>>(0, x, wbf, w1g, w2g, w1l, w2l, w1a, w2a,
                                 bidx, ag, al, aa, seg, cnt, xbf, out);
  k_main<<<NB, 256, 0, stream>>>(1, x, wbf, w1g, w2g, w1l, w2l, w1a, w2a,
                                 bidx, ag, al, aa, seg, cnt, xbf, out);
  k_main<<<NB, 256, 0, stream>>>(2, x, wbf, w1g, w2g, w1l, w2l, w1a, w2a,
                                 bidx, ag, al, aa, seg, cnt, xbf, out);
}

// Round 8
// 587.544 us; speedup vs baseline: 1.3574x; 1.3574x over previous
//
#include <hip/hip_runtime.h>

typedef unsigned short u16;
typedef __attribute__((ext_vector_type(8))) short short8;
typedef __attribute__((ext_vector_type(4))) float f32x4;
typedef __attribute__((ext_vector_type(4))) unsigned short u16x4;
typedef __attribute__((ext_vector_type(2))) unsigned u32x2;

#define NN 262144
#define CC 256
#define RR 64
#define GG 1024

// LDS byte-offset swizzle for row-major [node][feat] bf16 tiles.
#define SWZ(b, n) ((b) ^ (((n) & 7) << 4))
// slab row-swizzle ([16][64] f32, 256 B rows).
#define SSWZ(b, r) ((b) ^ (((r) & 7) << 4))

// ws layout (bytes):
//   0        : 6 bf16 weight matrices (w1g,w2g,w1l,w2l,w1a,w2a), 16384 elems each
//   196608   : seg float [1024][256] (raw sums; k_attn scales by 1/cnt)
//   1245184  : cnt int [1024]
//   1249280  : xbf — per-32-node-tile PRE-SWIZZLED bf16 x tiles, 16384 B each
#define XBFOFF 1249280
#define XBFSZ  ((size_t)NN * CC * 2)

static __device__ __forceinline__ u16 f2bf(float f) {
  unsigned u = __builtin_bit_cast(unsigned, f);
  u += 0x7fffu + ((u >> 16) & 1u);   // RNE
  return (u16)(u >> 16);
}

static __device__ __forceinline__ unsigned cvt_pk_bf16(float lo, float hi) {
  unsigned r;
  asm("v_cvt_pk_bf16_f32 %0, %1, %2" : "=v"(r) : "v"(lo), "v"(hi));
  return r;
}

static __device__ __forceinline__ void lgkm0() {
  __asm__ volatile("s_waitcnt lgkmcnt(0)" ::: "memory");
}

// async global->LDS, 16 B per lane (R6-proven pattern).
static __device__ __forceinline__ void gload_lds16(const void* g, void* l) {
  __builtin_amdgcn_global_load_lds(
      (const __attribute__((address_space(1))) void*)g,
      (__attribute__((address_space(3))) void*)l, 16, 0, 0);
}

#define MFMA16(a, b, c) __builtin_amdgcn_mfma_f32_16x16x32_bf16((a), (b), (c), 0, 0, 0)

// ---- k_prep: weight cvt (blocks 0..95) + seg/cnt zero (blocks 96..352) ----
__global__ void k_prep(const float* __restrict__ a0, const float* __restrict__ a1,
                       const float* __restrict__ a2, const float* __restrict__ a3,
                       const float* __restrict__ a4, const float* __restrict__ a5,
                       u16* __restrict__ dst, float* __restrict__ zbase) {
  int bid = blockIdx.x;
  if (bid < 96) {
    int m = bid >> 4;
    const float* s = (m == 0) ? a0 : (m == 1) ? a1 : (m == 2) ? a2
                   : (m == 3) ? a3 : (m == 4) ? a4 : a5;
    int off = (((bid & 15) << 8) | threadIdx.x) << 2;
    f32x4 v = *(const f32x4*)(s + off);
    u16x4 p;
    p[0] = f2bf(v[0]); p[1] = f2bf(v[1]); p[2] = f2bf(v[2]); p[3] = f2bf(v[3]);
    *(u16x4*)(dst + m * 16384 + off) = p;
  } else {
    int idx = (bid - 96) * 256 + threadIdx.x;
    ((f32x4*)zbase)[idx] = (f32x4){0.f, 0.f, 0.f, 0.f};
  }
}

// ============================================================================
// R8: per-phase weight-fragment BATCHES in registers (short8 wa[8], loaded
// back-to-back before the MFMA loop) -> one L2-latency stall per phase
// instead of one per fragment; each fragment feeds NT MFMAs.
// k_glb: NT=2 (32-node tiles), LDS 20480, wpe(5,5) budget 102 (need ~90).
// k_attn: NT=4 (64-node tiles), xbf staged via global_load_lds (0 staging
// VGPRs), LDS 40960 -> 4 blocks/CU, wpe(4,4) budget 128 (need ~95).
// Spill tripwire: WRITE_SIZE must stay at pure-output level.
// ============================================================================

// ---- K1: glb MLP + segment sums/counts + xbf export ----
#define ZB1 16384
__global__ __launch_bounds__(256)
__attribute__((amdgpu_waves_per_eu(5, 5))) void k_glb(
    const float* __restrict__ x, const u16* __restrict__ wbf,
    const int* __restrict__ bidx, const float* __restrict__ pa,
    float* __restrict__ seg, int* __restrict__ cnt,
    char* __restrict__ xbf) {
  __shared__ __align__(16) char smem[20480];
  const int tid = threadIdx.x;
  const int wave = tid >> 6, lane = tid & 63;
  const int low = lane & 15, quad = lane >> 4;
  const int node0 = blockIdx.x << 5;
  const float alpha = pa[0];
  const u16* w1 = wbf;
  const u16* w2 = wbf + 16384;

  const int lbv = bidx[node0 + (lane & 31)];

  // ---- stage x -> swizzled bf16 [32][256] (+ xbf export) ----
  const float* xsrc = x + (size_t)node0 * CC;
  char* xtile = xbf ? (xbf + ((size_t)blockIdx.x << 14)) : nullptr;
#pragma unroll
  for (int k = 0; k < 8; k++) {
    int f = k * 1024 + tid * 4;
    f32x4 v = *(const f32x4*)(xsrc + f);
    int node = f >> 8;
    u32x2 p;
    p[0] = cvt_pk_bf16(v[0], v[1]);
    p[1] = cvt_pk_bf16(v[2], v[3]);
    int off = SWZ(node * 512 + (f & 255) * 2, node);
    *(u32x2*)(smem + off) = p;
    if (xtile) *(u32x2*)(xtile + off) = p;
  }

  // ---- layer1 weight batch (8 back-to-back loads; one latency stall) ----
  short8 wa1[8];
  const u16* w1p = w1 + (wave * 16 + low) * CC;
#pragma unroll
  for (int ks = 0; ks < 8; ks++)
    wa1[ks] = *(const short8*)(w1p + ks * 32 + quad * 8);

  // node counts (wave 0, run-length on sorted bidx)
  if (wave == 0) {
    int cur = __shfl(lbv, 0), rl = 0;
#pragma unroll
    for (int n = 0; n < 32; n++) {
      int b = __shfl(lbv, n);
      if (b != cur) { if (lane == 0) atomicAdd(cnt + cur, rl); rl = 0; cur = b; }
      rl++;
    }
    if (lane == 0) atomicAdd(cnt + cur, rl);
  }
  __syncthreads();   // B1: x visible

  // ---- layer1: each frag feeds 2 MFMAs ----
  f32x4 z[2] = {};
#pragma unroll
  for (int ks = 0; ks < 8; ks++) {
#pragma unroll
    for (int nt = 0; nt < 2; nt++) {
      int node = nt * 16 + low;
      short8 xf = *(const short8*)(smem + SWZ(node * 512 + ks * 64 + quad * 16, node));
      z[nt] = MFMA16(wa1[ks], xf, z[nt]);
    }
  }
  // layer2 weight batch
  short8 wa2[8];
#pragma unroll
  for (int ks2 = 0; ks2 < 2; ks2++)
#pragma unroll
    for (int mt = 0; mt < 4; mt++)
      wa2[ks2 * 4 + mt] =
          *(const short8*)(w2 + (wave * 64 + mt * 16 + low) * RR + ks2 * 32 + quad * 8);
  // PReLU + stage z -> ZB (disjoint from x)
#pragma unroll
  for (int nt = 0; nt < 2; nt++) {
    float v0 = z[nt][0], v1 = z[nt][1], v2 = z[nt][2], v3 = z[nt][3];
    v0 = v0 >= 0.f ? v0 : alpha * v0;
    v1 = v1 >= 0.f ? v1 : alpha * v1;
    v2 = v2 >= 0.f ? v2 : alpha * v2;
    v3 = v3 >= 0.f ? v3 : alpha * v3;
    int node = nt * 16 + low;
    u32x2 p;
    p[0] = cvt_pk_bf16(v0, v1);
    p[1] = cvt_pk_bf16(v2, v3);
    *(u32x2*)(smem + ZB1 + SWZ(node * 128 + wave * 32 + quad * 8, node)) = p;
  }
  __syncthreads();   // B2: z visible; x reads drained (slab overlays XB)

  // ---- layer2 + segment reduce, per nt ----
  char* slab = smem + wave * 4096;
#pragma unroll
  for (int nt = 0; nt < 2; nt++) {
    int node = nt * 16 + low;
    f32x4 g[4] = {};
#pragma unroll
    for (int ks2 = 0; ks2 < 2; ks2++) {
      short8 zf = *(const short8*)(smem + ZB1 + SWZ(node * 128 + ks2 * 64 + quad * 16, node));
#pragma unroll
      for (int mt = 0; mt < 4; mt++)
        g[mt] = MFMA16(wa2[ks2 * 4 + mt], zf, g[mt]);
    }
#pragma unroll
    for (int mt = 0; mt < 4; mt++)
      *(f32x4*)(slab + SSWZ(low * 256 + mt * 64 + quad * 16, low)) = g[mt];
    lgkm0();
    float acc = 0.f;
    int cur = __shfl(lbv, nt * 16);
#pragma unroll
    for (int n = 0; n < 16; n++) {
      int b = __shfl(lbv, nt * 16 + n);
      if (b != cur) {
        atomicAdd(seg + (size_t)cur * CC + wave * 64 + lane, acc);
        acc = 0.f; cur = b;
      }
      acc += *(const float*)(slab + SSWZ(n * 256 + lane * 4, n));
    }
    atomicAdd(seg + (size_t)cur * CC + wave * 64 + lane, acc);
    lgkm0();
  }
}

// ---- K3: local MLP + gather(1/cnt fused) + attn MLP + sigmoid ----
// NT=4: 64-node tiles, 4096 blocks. LDS: XB 0..32768 ([64][512B] swz),
// ZB 32768..40960 ([64][128B] swz).
#define ZB3 32768
template <int USE_XBF>
__global__ __launch_bounds__(256)
__attribute__((amdgpu_waves_per_eu(4, 4))) void k_attn(
    const float* __restrict__ x, const char* __restrict__ xbf,
    const u16* __restrict__ wbf,
    const int* __restrict__ bidx, const float* __restrict__ seg,
    const int* __restrict__ cnt,
    const float* __restrict__ pal, const float* __restrict__ paa,
    float* __restrict__ out) {
  __shared__ __align__(16) char smem[40960];
  const int tid = threadIdx.x;
  const int wave = tid >> 6, lane = tid & 63;
  const int low = lane & 15, quad = lane >> 4;
  const int node0 = blockIdx.x << 6;
  const float al = pal[0], aa = paa[0];
  const u16* w1l = wbf + 2 * 16384;
  const u16* w2l = wbf + 3 * 16384;
  const u16* w1a = wbf + 4 * 16384;
  const u16* w2a = wbf + 5 * 16384;

  // ---- stage x tile (32 KB) ----
  if (USE_XBF) {
    // two consecutive pre-swizzled 16 KB tiles == [64][512B] swz layout
    const char* gsrc = xbf + ((size_t)blockIdx.x << 15) + wave * 1024 + lane * 16;
    char* ldst = smem + wave * 1024 + lane * 16;
#pragma unroll
    for (int j = 0; j < 8; j++)
      gload_lds16(gsrc + j * 4096, ldst + j * 4096);
  } else {
    const float* xsrc = x + (size_t)node0 * CC;
#pragma unroll
    for (int k = 0; k < 16; k++) {
      int f = k * 1024 + tid * 4;
      f32x4 v = *(const f32x4*)(xsrc + f);
      int node = f >> 8;
      u32x2 p;
      p[0] = cvt_pk_bf16(v[0], v[1]);
      p[1] = cvt_pk_bf16(v[2], v[3]);
      *(u32x2*)(smem + SWZ(node * 512 + (f & 255) * 2, node)) = p;
    }
  }

  // early: per-node graph id + count; layer1 weight batch
  int bb[4], cc2[4];
#pragma unroll
  for (int nt = 0; nt < 4; nt++) bb[nt] = bidx[node0 + nt * 16 + low];
#pragma unroll
  for (int nt = 0; nt < 4; nt++) cc2[nt] = cnt[bb[nt]];
  short8 wa[8];
  {
    const u16* w1p = w1l + (wave * 16 + low) * CC;
#pragma unroll
    for (int ks = 0; ks < 8; ks++)
      wa[ks] = *(const short8*)(w1p + ks * 32 + quad * 8);
  }
  __syncthreads();   // B1: x visible (vmcnt(0) drain covers global_load_lds)

  // ---- local layer1: each frag feeds 4 MFMAs ----
  f32x4 z[4] = {};
#pragma unroll
  for (int ks = 0; ks < 8; ks++) {
#pragma unroll
    for (int nt = 0; nt < 4; nt++) {
      int node = nt * 16 + low;
      short8 xf = *(const short8*)(smem + SWZ(node * 512 + ks * 64 + quad * 16, node));
      z[nt] = MFMA16(wa[ks], xf, z[nt]);
    }
  }
  // layer2 weight batch (reuses wa regs)
  short8 wb[8];
#pragma unroll
  for (int ks2 = 0; ks2 < 2; ks2++)
#pragma unroll
    for (int mt = 0; mt < 4; mt++)
      wb[ks2 * 4 + mt] =
          *(const short8*)(w2l + (wave * 64 + mt * 16 + low) * RR + ks2 * 32 + quad * 8);
  // PReLU + stage z -> ZB (disjoint from XB)
#pragma unroll
  for (int nt = 0; nt < 4; nt++) {
    float v0 = z[nt][0], v1 = z[nt][1], v2 = z[nt][2], v3 = z[nt][3];
    v0 = v0 >= 0.f ? v0 : al * v0;
    v1 = v1 >= 0.f ? v1 : al * v1;
    v2 = v2 >= 0.f ? v2 : al * v2;
    v3 = v3 >= 0.f ? v3 : al * v3;
    int node = nt * 16 + low;
    u32x2 p;
    p[0] = cvt_pk_bf16(v0, v1);
    p[1] = cvt_pk_bf16(v2, v3);
    *(u32x2*)(smem + ZB3 + SWZ(node * 128 + wave * 32 + quad * 8, node)) = p;
  }
  __syncthreads();   // B2: z visible; XB reads drained (h may overwrite XB)

  // ---- local layer2 + gather + h-stage, per nt ----
#pragma unroll
  for (int nt = 0; nt < 4; nt++) {
    int node = nt * 16 + low;
    const float* srow = seg + (size_t)bb[nt] * CC + wave * 64;
    f32x4 sv[4];
#pragma unroll
    for (int mt = 0; mt < 4; mt++) sv[mt] = *(const f32x4*)(srow + mt * 16 + quad * 4);
    f32x4 loc[4] = {};
#pragma unroll
    for (int ks2 = 0; ks2 < 2; ks2++) {
      short8 zf = *(const short8*)(smem + ZB3 + SWZ(node * 128 + ks2 * 64 + quad * 16, node));
#pragma unroll
      for (int mt = 0; mt < 4; mt++)
        loc[mt] = MFMA16(wb[ks2 * 4 + mt], zf, loc[mt]);
    }
    float inv = (cc2[nt] > 0) ? __builtin_amdgcn_rcpf((float)cc2[nt]) : 0.0f;
#pragma unroll
    for (int mt = 0; mt < 4; mt++) {
      u32x2 p;
      p[0] = cvt_pk_bf16(fmaf(sv[mt][0], inv, loc[mt][0]),
                         fmaf(sv[mt][1], inv, loc[mt][1]));
      p[1] = cvt_pk_bf16(fmaf(sv[mt][2], inv, loc[mt][2]),
                         fmaf(sv[mt][3], inv, loc[mt][3]));
      *(u32x2*)(smem + SWZ(node * 512 + wave * 128 + mt * 32 + quad * 8, node)) = p;
    }
  }
  // attn layer1 weight batch
  {
    const u16* w1p = w1a + (wave * 16 + low) * CC;
#pragma unroll
    for (int ks = 0; ks < 8; ks++)
      wa[ks] = *(const short8*)(w1p + ks * 32 + quad * 8);
  }
  __syncthreads();   // B3: h visible + ZB reads drained

  // ---- attn layer1 ----
  f32x4 z2[4] = {};
#pragma unroll
  for (int ks = 0; ks < 8; ks++) {
#pragma unroll
    for (int nt = 0; nt < 4; nt++) {
      int node = nt * 16 + low;
      short8 hf = *(const short8*)(smem + SWZ(node * 512 + ks * 64 + quad * 16, node));
      z2[nt] = MFMA16(wa[ks], hf, z2[nt]);
    }
  }
  // attn layer2 weight batch
#pragma unroll
  for (int ks2 = 0; ks2 < 2; ks2++)
#pragma unroll
    for (int mt = 0; mt < 4; mt++)
      wb[ks2 * 4 + mt] =
          *(const short8*)(w2a + (wave * 64 + mt * 16 + low) * RR + ks2 * 32 + quad * 8);
#pragma unroll
  for (int nt = 0; nt < 4; nt++) {
    float v0 = z2[nt][0], v1 = z2[nt][1], v2 = z2[nt][2], v3 = z2[nt][3];
    v0 = v0 >= 0.f ? v0 : aa * v0;
    v1 = v1 >= 0.f ? v1 : aa * v1;
    v2 = v2 >= 0.f ? v2 : aa * v2;
    v3 = v3 >= 0.f ? v3 : aa * v3;
    int node = nt * 16 + low;
    u32x2 p;
    p[0] = cvt_pk_bf16(v0, v1);
    p[1] = cvt_pk_bf16(v2, v3);
    *(u32x2*)(smem + ZB3 + SWZ(node * 128 + wave * 32 + quad * 8, node)) = p;
  }
  __syncthreads();   // B4: z2 visible

  // ---- attn layer2 + sigmoid + direct store ----
#pragma unroll
  for (int nt = 0; nt < 4; nt++) {
    int node = nt * 16 + low;
    f32x4 o[4] = {};
#pragma unroll
    for (int ks2 = 0; ks2 < 2; ks2++) {
      short8 zf = *(const short8*)(smem + ZB3 + SWZ(node * 128 + ks2 * 64 + quad * 16, node));
#pragma unroll
      for (int mt = 0; mt < 4; mt++)
        o[mt] = MFMA16(wb[ks2 * 4 + mt], zf, o[mt]);
    }
    float* orow = out + (size_t)(node0 + node) * CC + wave * 64;
#pragma unroll
    for (int mt = 0; mt < 4; mt++) {
#pragma unroll
      for (int i = 0; i < 4; i++)
        o[mt][i] = __builtin_amdgcn_rcpf(1.0f + __expf(-o[mt][i]));
      *(f32x4*)(orow + mt * 16 + quad * 4) = o[mt];
    }
  }
}

extern "C" void kernel_launch(void* const* d_in, const int* in_sizes, int n_in,
                              void* d_out, int out_size, void* d_ws, size_t ws_size,
                              hipStream_t stream) {
  (void)in_sizes; (void)n_in; (void)out_size;
  const float* x   = (const float*)d_in[0];
  const float* w1g = (const float*)d_in[1];
  const float* ag  = (const float*)d_in[2];
  const float* w2g = (const float*)d_in[3];
  const float* w1l = (const float*)d_in[4];
  const float* al  = (const float*)d_in[5];
  const float* w2l = (const float*)d_in[6];
  const float* w1a = (const float*)d_in[7];
  const float* aa  = (const float*)d_in[8];
  const float* w2a = (const float*)d_in[9];
  const int* bidx  = (const int*)d_in[10];
  float* out = (float*)d_out;

  u16* wbf   = (u16*)d_ws;
  float* seg = (float*)((char*)d_ws + 196608);
  int* cnt   = (int*)((char*)d_ws + 196608 + 1048576);
  char* xbf  = (ws_size >= (size_t)XBFOFF + XBFSZ) ? ((char*)d_ws + XBFOFF) : nullptr;

  k_prep<<<353, 256, 0, stream>>>(w1g, w2g, w1l, w2l, w1a, w2a, wbf, seg);
  k_glb<<<NN / 32, 256, 0, stream>>>(x, wbf, bidx, ag, seg, cnt, xbf);
  if (xbf)
    k_attn<1><<<NN / 64, 256, 0, stream>>>(x, xbf, wbf, bidx, seg, cnt, al, aa, out);
  else
    k_attn<0><<<NN / 64, 256, 0, stream>>>(x, xbf, wbf, bidx, seg, cnt, al, aa, out);
}